// Round 1
// baseline (508.848 us; speedup 1.0000x reference)
//
#include <hip/hip_runtime.h>
#include <hip/hip_bf16.h>
#include <cstdint>
#include <cstddef>

// MHA forward: out = (softmax(QK^T/8) V) Wo + bo, plus p_attn output.
// B=8, S=1024, H=16, DK=64, D_MODEL=1024, WORD_DIM=768. All inputs fp32.
// Strategy: bf16 MFMA (16x16x32) everywhere, fp32 accumulate.

#define H_ 16
#define DK_ 64
#define DM_ 1024
#define WD_ 768
#define B_ 8
#define S_ 1024

typedef float f32x4 __attribute__((ext_vector_type(4)));
typedef __bf16 bf16x8 __attribute__((ext_vector_type(8)));
typedef short s16x8 __attribute__((ext_vector_type(8)));

__device__ __forceinline__ unsigned short f2bf(float x) {
  unsigned int u = __builtin_bit_cast(unsigned int, x);
  u += 0x7FFFu + ((u >> 16) & 1u);  // RNE (no NaN inputs here)
  return (unsigned short)(u >> 16);
}

__device__ __forceinline__ f32x4 mfma16(bf16x8 a, bf16x8 b, f32x4 c) {
  return __builtin_amdgcn_mfma_f32_16x16x32_bf16(a, b, c, 0, 0, 0);
}

__device__ __forceinline__ bf16x8 ld_bf8(const unsigned short* p) {
  return *reinterpret_cast<const bf16x8*>(p);
}

// ---------------- conversion kernels ----------------

__global__ void k_f32_to_bf16(const float* __restrict__ in,
                              unsigned short* __restrict__ out, int n) {
  int i0 = (blockIdx.x * blockDim.x + threadIdx.x) * 8;
  int stride = gridDim.x * blockDim.x * 8;
  for (int i = i0; i < n; i += stride) {
    float4 a = *reinterpret_cast<const float4*>(in + i);
    float4 b = *reinterpret_cast<const float4*>(in + i + 4);
    s16x8 o;
    o[0] = (short)f2bf(a.x); o[1] = (short)f2bf(a.y);
    o[2] = (short)f2bf(a.z); o[3] = (short)f2bf(a.w);
    o[4] = (short)f2bf(b.x); o[5] = (short)f2bf(b.y);
    o[6] = (short)f2bf(b.z); o[7] = (short)f2bf(b.w);
    *reinterpret_cast<s16x8*>(out + i) = o;
  }
}

// W[K][N] fp32 -> Wt[N][K] bf16 (transpose + convert), 32x32 tiles
__global__ void k_tconv(const float* __restrict__ W,
                        unsigned short* __restrict__ Wt, int K, int N) {
  __shared__ float t[32][33];
  int n0 = blockIdx.x * 32, k0 = blockIdx.y * 32;
  int tx = threadIdx.x, ty = threadIdx.y;
  for (int dy = ty; dy < 32; dy += 8)
    t[dy][tx] = W[(size_t)(k0 + dy) * N + n0 + tx];
  __syncthreads();
  for (int dy = ty; dy < 32; dy += 8)
    Wt[(size_t)(n0 + dy) * K + k0 + tx] = f2bf(t[tx][dy]);
}

// ---------------- generic GEMM: C = A[M,K] @ Bt[N,K]^T + bias ----------------
// EPI 0: write bf16 head-split [B,H,S,DK]   (for Q, K projections)
// EPI 1: write bf16 transposed [B,H,DK,S]   (for V projection)
// EPI 2: write fp32 [M, DM_] (+bias)        (final output projection)
template <int EPI>
__global__ __launch_bounds__(256) void k_gemm_bt(
    const unsigned short* __restrict__ A, const unsigned short* __restrict__ Bt,
    const float* __restrict__ bias, void* __restrict__ outp, int M, int N, int K) {
  __shared__ unsigned short As[128][40];
  __shared__ unsigned short Bs[128][40];
  const int t = threadIdx.x;
  const int lane = t & 63, wid = t >> 6;
  const int l16 = lane & 15, lhi = lane >> 4;
  const int m0 = blockIdx.y * 128, n0 = blockIdx.x * 128;
  const int wm = (wid >> 1) * 64, wn = (wid & 1) * 64;

  f32x4 acc[4][4] = {};

  const int sr = t >> 1;         // 0..127
  const int sc = (t & 1) * 16;   // 0 / 16

  for (int k0 = 0; k0 < K; k0 += 32) {
    {
      const unsigned short* sa = A + (size_t)(m0 + sr) * K + k0 + sc;
      s16x8 a0 = *reinterpret_cast<const s16x8*>(sa);
      s16x8 a1 = *reinterpret_cast<const s16x8*>(sa + 8);
      const unsigned short* sb = Bt + (size_t)(n0 + sr) * K + k0 + sc;
      s16x8 b0 = *reinterpret_cast<const s16x8*>(sb);
      s16x8 b1 = *reinterpret_cast<const s16x8*>(sb + 8);
      *reinterpret_cast<s16x8*>(&As[sr][sc]) = a0;
      *reinterpret_cast<s16x8*>(&As[sr][sc + 8]) = a1;
      *reinterpret_cast<s16x8*>(&Bs[sr][sc]) = b0;
      *reinterpret_cast<s16x8*>(&Bs[sr][sc + 8]) = b1;
    }
    __syncthreads();
    bf16x8 aF[4], bF[4];
#pragma unroll
    for (int i = 0; i < 4; ++i)
      aF[i] = ld_bf8(&As[wm + i * 16 + l16][lhi * 8]);
#pragma unroll
    for (int j = 0; j < 4; ++j)
      bF[j] = ld_bf8(&Bs[wn + j * 16 + l16][lhi * 8]);
#pragma unroll
    for (int i = 0; i < 4; ++i)
#pragma unroll
      for (int j = 0; j < 4; ++j)
        acc[i][j] = mfma16(aF[i], bF[j], acc[i][j]);
    __syncthreads();
  }

#pragma unroll
  for (int i = 0; i < 4; ++i) {
#pragma unroll
    for (int j = 0; j < 4; ++j) {
#pragma unroll
      for (int r = 0; r < 4; ++r) {
        int m = m0 + wm + i * 16 + lhi * 4 + r;
        int n = n0 + wn + j * 16 + l16;
        float v = acc[i][j][r] + bias[n];
        if (EPI == 2) {
          reinterpret_cast<float*>(outp)[(size_t)m * DM_ + n] = v;
        } else {
          int b = m >> 10, s = m & (S_ - 1);
          int h = n >> 6, d = n & (DK_ - 1);
          size_t idx;
          if (EPI == 0) idx = ((size_t)(b * H_ + h) * S_ + s) * DK_ + d;
          else          idx = ((size_t)(b * H_ + h) * DK_ + d) * S_ + s;
          reinterpret_cast<unsigned short*>(outp)[idx] = f2bf(v);
        }
      }
    }
  }
}

// ---------------- scores + softmax: P[bh, q, k] = softmax(Q K^T / 8) ----------------
// Block: 512 threads (8 waves). One (b,h) + 32 q-rows per block.
// Wave w computes cols [w*128, w*128+128). Scores kept in registers.
__global__ __launch_bounds__(512) void k_scores(
    const unsigned short* __restrict__ Qh, const unsigned short* __restrict__ Kh,
    float* __restrict__ P) {
  __shared__ unsigned short Qs[32][72];
  __shared__ float red[32][8];
  __shared__ float rowM[32];
  __shared__ float rowS[32];
  const int t = threadIdx.x;
  const int lane = t & 63, wid = t >> 6;
  const int l16 = lane & 15, lhi = lane >> 4;
  const int bh = blockIdx.y;
  const int q0 = blockIdx.x * 32;
  const unsigned short* Qbase = Qh + (size_t)bh * S_ * DK_;
  const unsigned short* Kbase = Kh + (size_t)bh * S_ * DK_;

  if (t < 256) {
    int r = t >> 3, c = (t & 7) * 8;
    *reinterpret_cast<s16x8*>(&Qs[r][c]) =
        *reinterpret_cast<const s16x8*>(Qbase + (size_t)(q0 + r) * DK_ + c);
  }
  __syncthreads();

  f32x4 acc[2][8] = {};
  const int n0 = wid * 128;
#pragma unroll
  for (int ks = 0; ks < 2; ++ks) {
    bf16x8 aF[2];
#pragma unroll
    for (int i = 0; i < 2; ++i)
      aF[i] = ld_bf8(&Qs[i * 16 + l16][ks * 32 + lhi * 8]);
#pragma unroll
    for (int j = 0; j < 8; ++j) {
      bf16x8 bF = *reinterpret_cast<const bf16x8*>(
          Kbase + (size_t)(n0 + j * 16 + l16) * DK_ + ks * 32 + lhi * 8);
#pragma unroll
      for (int i = 0; i < 2; ++i)
        acc[i][j] = mfma16(aF[i], bF, acc[i][j]);
    }
  }

  // scale by 1/sqrt(DK)=0.125
#pragma unroll
  for (int i = 0; i < 2; ++i)
#pragma unroll
    for (int j = 0; j < 8; ++j)
#pragma unroll
      for (int r = 0; r < 4; ++r) acc[i][j][r] *= 0.125f;

  // ---- row max (within wave: 16-lane butterfly; cross-wave via LDS) ----
#pragma unroll
  for (int i = 0; i < 2; ++i) {
#pragma unroll
    for (int r = 0; r < 4; ++r) {
      float m = acc[i][0][r];
#pragma unroll
      for (int j = 1; j < 8; ++j) m = fmaxf(m, acc[i][j][r]);
      for (int off = 1; off < 16; off <<= 1) m = fmaxf(m, __shfl_xor(m, off));
      if (l16 == 0) red[i * 16 + lhi * 4 + r][wid] = m;
    }
  }
  __syncthreads();
  if (t < 32) {
    float m = red[t][0];
#pragma unroll
    for (int w = 1; w < 8; ++w) m = fmaxf(m, red[t][w]);
    rowM[t] = m;
  }
  __syncthreads();

  // ---- exp + row sum ----
#pragma unroll
  for (int i = 0; i < 2; ++i) {
#pragma unroll
    for (int r = 0; r < 4; ++r) {
      int q = i * 16 + lhi * 4 + r;
      float mq = rowM[q];
      float s = 0.f;
#pragma unroll
      for (int j = 0; j < 8; ++j) {
        float e = __expf(acc[i][j][r] - mq);
        acc[i][j][r] = e;
        s += e;
      }
      for (int off = 1; off < 16; off <<= 1) s += __shfl_xor(s, off);
      if (l16 == 0) red[q][wid] = s;
    }
  }
  __syncthreads();
  if (t < 32) {
    float s = red[t][0];
#pragma unroll
    for (int w = 1; w < 8; ++w) s += red[t][w];
    rowS[t] = s;
  }
  __syncthreads();

  // ---- normalize + write fp32 P ----
#pragma unroll
  for (int i = 0; i < 2; ++i) {
#pragma unroll
    for (int r = 0; r < 4; ++r) {
      int q = i * 16 + lhi * 4 + r;
      float inv = 1.f / rowS[q];
      float* prow = P + ((size_t)bh * S_ + q0 + q) * S_ + n0;
#pragma unroll
      for (int j = 0; j < 8; ++j) prow[j * 16 + l16] = acc[i][j][r] * inv;
    }
  }
}

// ---------------- PV: X[b,s,h*64+d] = sum_k P[bh,s,k] * V[bh,k,d] ----------------
// P fp32 (from d_out), Vt bf16 [B,H,DK,S]. Block 256 thr (4 waves), tile 128x64.
__global__ __launch_bounds__(256) void k_pv(
    const float* __restrict__ P, const unsigned short* __restrict__ Vt,
    unsigned short* __restrict__ Xb) {
  __shared__ unsigned short Ps[128][40];
  __shared__ unsigned short Vs[64][40];
  const int t = threadIdx.x;
  const int lane = t & 63, wid = t >> 6;
  const int l16 = lane & 15, lhi = lane >> 4;
  const int bh = blockIdx.y;
  const int s0 = blockIdx.x * 128;
  const float* Pbase = P + (size_t)bh * S_ * S_;
  const unsigned short* Vbase = Vt + (size_t)bh * DK_ * S_;

  f32x4 acc[2][4] = {};

  for (int kk = 0; kk < S_; kk += 32) {
    {
      int r = t >> 1, c = (t & 1) * 16;
      const float* src = Pbase + (size_t)(s0 + r) * S_ + kk + c;
      float4 v0 = *reinterpret_cast<const float4*>(src);
      float4 v1 = *reinterpret_cast<const float4*>(src + 4);
      float4 v2 = *reinterpret_cast<const float4*>(src + 8);
      float4 v3 = *reinterpret_cast<const float4*>(src + 12);
      s16x8 o0, o1;
      o0[0] = (short)f2bf(v0.x); o0[1] = (short)f2bf(v0.y);
      o0[2] = (short)f2bf(v0.z); o0[3] = (short)f2bf(v0.w);
      o0[4] = (short)f2bf(v1.x); o0[5] = (short)f2bf(v1.y);
      o0[6] = (short)f2bf(v1.z); o0[7] = (short)f2bf(v1.w);
      o1[0] = (short)f2bf(v2.x); o1[1] = (short)f2bf(v2.y);
      o1[2] = (short)f2bf(v2.z); o1[3] = (short)f2bf(v2.w);
      o1[4] = (short)f2bf(v3.x); o1[5] = (short)f2bf(v3.y);
      o1[6] = (short)f2bf(v3.z); o1[7] = (short)f2bf(v3.w);
      *reinterpret_cast<s16x8*>(&Ps[r][c]) = o0;
      *reinterpret_cast<s16x8*>(&Ps[r][c + 8]) = o1;
    }
    if (t < 128) {
      int r = t >> 1, c = (t & 1) * 16;
      const unsigned short* src = Vbase + (size_t)r * S_ + kk + c;
      s16x8 w0 = *reinterpret_cast<const s16x8*>(src);
      s16x8 w1 = *reinterpret_cast<const s16x8*>(src + 8);
      *reinterpret_cast<s16x8*>(&Vs[r][c]) = w0;
      *reinterpret_cast<s16x8*>(&Vs[r][c + 8]) = w1;
    }
    __syncthreads();
    bf16x8 aF[2], bF[4];
#pragma unroll
    for (int i = 0; i < 2; ++i)
      aF[i] = ld_bf8(&Ps[wid * 32 + i * 16 + l16][lhi * 8]);
#pragma unroll
    for (int j = 0; j < 4; ++j)
      bF[j] = ld_bf8(&Vs[j * 16 + l16][lhi * 8]);
#pragma unroll
    for (int i = 0; i < 2; ++i)
#pragma unroll
      for (int j = 0; j < 4; ++j)
        acc[i][j] = mfma16(aF[i], bF[j], acc[i][j]);
    __syncthreads();
  }

  const int b = bh >> 4, h = bh & 15;
#pragma unroll
  for (int i = 0; i < 2; ++i) {
#pragma unroll
    for (int j = 0; j < 4; ++j) {
#pragma unroll
      for (int r = 0; r < 4; ++r) {
        int s = s0 + wid * 32 + i * 16 + lhi * 4 + r;
        int d = j * 16 + l16;
        Xb[(size_t)(b * S_ + s) * DM_ + h * DK_ + d] = f2bf(acc[i][j][r]);
      }
    }
  }
}

// ---------------- launch ----------------

extern "C" void kernel_launch(void* const* d_in, const int* in_sizes, int n_in,
                              void* d_out, int out_size, void* d_ws, size_t ws_size,
                              hipStream_t stream) {
  const float* query = (const float*)d_in[0];
  const float* key   = (const float*)d_in[1];
  const float* value = (const float*)d_in[2];
  const float* Wq = (const float*)d_in[3];
  const float* bq = (const float*)d_in[4];
  const float* Wk = (const float*)d_in[5];
  const float* bk = (const float*)d_in[6];
  const float* Wv = (const float*)d_in[7];
  const float* bv = (const float*)d_in[8];
  const float* Wo = (const float*)d_in[9];
  const float* bo = (const float*)d_in[10];

  char* ws = (char*)d_ws;
  size_t off = 0;
  auto alloc = [&](size_t bytes) {
    void* p = ws + off;
    off += (bytes + 255) & ~(size_t)255;
    return p;
  };
  unsigned short* qb  = (unsigned short*)alloc((size_t)B_ * S_ * WD_ * 2);
  unsigned short* kb  = (unsigned short*)alloc((size_t)B_ * S_ * WD_ * 2);
  unsigned short* vb  = (unsigned short*)alloc((size_t)B_ * S_ * WD_ * 2);
  unsigned short* Wqt = (unsigned short*)alloc((size_t)DM_ * WD_ * 2);
  unsigned short* Wkt = (unsigned short*)alloc((size_t)DM_ * WD_ * 2);
  unsigned short* Wvt = (unsigned short*)alloc((size_t)DM_ * WD_ * 2);
  unsigned short* Wot = (unsigned short*)alloc((size_t)DM_ * DM_ * 2);
  unsigned short* Qh  = (unsigned short*)alloc((size_t)B_ * H_ * S_ * DK_ * 2);
  unsigned short* Kh  = (unsigned short*)alloc((size_t)B_ * H_ * S_ * DK_ * 2);
  unsigned short* Vt  = (unsigned short*)alloc((size_t)B_ * H_ * DK_ * S_ * 2);
  unsigned short* Xb  = (unsigned short*)alloc((size_t)B_ * S_ * DM_ * 2);

  float* out = (float*)d_out;
  float* P = out + (size_t)B_ * S_ * DM_;  // p_attn region

  const int nAct = B_ * S_ * WD_;
  k_f32_to_bf16<<<dim3(1024), 256, 0, stream>>>(query, qb, nAct);
  k_f32_to_bf16<<<dim3(1024), 256, 0, stream>>>(key, kb, nAct);
  k_f32_to_bf16<<<dim3(1024), 256, 0, stream>>>(value, vb, nAct);
  k_tconv<<<dim3(DM_ / 32, WD_ / 32), dim3(32, 8), 0, stream>>>(Wq, Wqt, WD_, DM_);
  k_tconv<<<dim3(DM_ / 32, WD_ / 32), dim3(32, 8), 0, stream>>>(Wk, Wkt, WD_, DM_);
  k_tconv<<<dim3(DM_ / 32, WD_ / 32), dim3(32, 8), 0, stream>>>(Wv, Wvt, WD_, DM_);
  k_tconv<<<dim3(DM_ / 32, DM_ / 32), dim3(32, 8), 0, stream>>>(Wo, Wot, DM_, DM_);

  const int M = B_ * S_;
  k_gemm_bt<0><<<dim3(DM_ / 128, M / 128), 256, 0, stream>>>(qb, Wqt, bq, Qh, M, DM_, WD_);
  k_gemm_bt<0><<<dim3(DM_ / 128, M / 128), 256, 0, stream>>>(kb, Wkt, bk, Kh, M, DM_, WD_);
  k_gemm_bt<1><<<dim3(DM_ / 128, M / 128), 256, 0, stream>>>(vb, Wvt, bv, Vt, M, DM_, WD_);

  k_scores<<<dim3(S_ / 32, B_ * H_), 512, 0, stream>>>(Qh, Kh, P);
  k_pv<<<dim3(S_ / 128, B_ * H_), 256, 0, stream>>>(P, Vt, Xb);
  k_gemm_bt<2><<<dim3(DM_ / 128, M / 128), 256, 0, stream>>>(Xb, Wot, bo, out, M, DM_, DM_);
}

// Round 2
// 453.257 us; speedup vs baseline: 1.1226x; 1.1226x over previous
//
#include <hip/hip_runtime.h>
#include <hip/hip_bf16.h>
#include <cstdint>
#include <cstddef>

// MHA forward: out = (softmax(QK^T/8) V) Wo + bo, plus p_attn output (fp32).
// B=8, S=1024, H=16, DK=64, D_MODEL=1024, WORD_DIM=768. Inputs fp32.
// bf16 MFMA 16x16x32, fp32 accumulate. Fused scores+softmax+PV kernel.

#define H_ 16
#define DK_ 64
#define DM_ 1024
#define WD_ 768
#define B_ 8
#define S_ 1024

typedef float f32x4 __attribute__((ext_vector_type(4)));
typedef __bf16 bf16x8 __attribute__((ext_vector_type(8)));
typedef short s16x8 __attribute__((ext_vector_type(8)));

__device__ __forceinline__ unsigned short f2bf(float x) {
  unsigned int u = __builtin_bit_cast(unsigned int, x);
  u += 0x7FFFu + ((u >> 16) & 1u);  // RNE (no NaNs here)
  return (unsigned short)(u >> 16);
}

__device__ __forceinline__ f32x4 mfma16(bf16x8 a, bf16x8 b, f32x4 c) {
  return __builtin_amdgcn_mfma_f32_16x16x32_bf16(a, b, c, 0, 0, 0);
}

__device__ __forceinline__ bf16x8 ld_bf8(const unsigned short* p) {
  return *reinterpret_cast<const bf16x8*>(p);
}

// W[K][N] fp32 -> Wt[N][K] bf16 (transpose + convert), 32x32 tiles
__global__ void k_tconv(const float* __restrict__ W,
                        unsigned short* __restrict__ Wt, int K, int N) {
  __shared__ float t[32][33];
  int n0 = blockIdx.x * 32, k0 = blockIdx.y * 32;
  int tx = threadIdx.x, ty = threadIdx.y;
  for (int dy = ty; dy < 32; dy += 8)
    t[dy][tx] = W[(size_t)(k0 + dy) * N + n0 + tx];
  __syncthreads();
  for (int dy = ty; dy < 32; dy += 8)
    Wt[(size_t)(n0 + dy) * K + k0 + tx] = f2bf(t[tx][dy]);
}

// ---------------- QKV projection GEMM ----------------
// C = A[M,768] (fp32, converted in staging) @ Wt[1024,768]^T + bias
// blockIdx.z: 0=Q -> Qb bf16 [M][DM], 1=K -> Kb bf16 [M][DM],
//             2=V -> Vt bf16 [B,H,DK,S] (transposed for PV B-fragments)
__global__ __launch_bounds__(256) void k_gemm_qkv(
    const float* __restrict__ A0, const float* __restrict__ A1,
    const float* __restrict__ A2, const unsigned short* __restrict__ W0,
    const unsigned short* __restrict__ W1, const unsigned short* __restrict__ W2,
    const float* __restrict__ b0p, const float* __restrict__ b1p,
    const float* __restrict__ b2p, unsigned short* __restrict__ Qb,
    unsigned short* __restrict__ Kb, unsigned short* __restrict__ Vt) {
  const int z = blockIdx.z;
  const float* A = (z == 0) ? A0 : (z == 1) ? A1 : A2;
  const unsigned short* Bt = (z == 0) ? W0 : (z == 1) ? W1 : W2;
  const float* bias = (z == 0) ? b0p : (z == 1) ? b1p : b2p;

  __shared__ unsigned short As[128][40];
  __shared__ unsigned short Bs[128][40];
  const int t = threadIdx.x;
  const int lane = t & 63, wid = t >> 6;
  const int l16 = lane & 15, lhi = lane >> 4;
  const int m0 = blockIdx.y * 128, n0 = blockIdx.x * 128;
  const int wm = (wid >> 1) * 64, wn = (wid & 1) * 64;

  f32x4 acc[4][4] = {};
  const int sr = t >> 1, sc = (t & 1) * 16;

  for (int k0 = 0; k0 < WD_; k0 += 32) {
    {
      const float* sa = A + (size_t)(m0 + sr) * WD_ + k0 + sc;
      float4 f0 = *reinterpret_cast<const float4*>(sa);
      float4 f1 = *reinterpret_cast<const float4*>(sa + 4);
      float4 f2 = *reinterpret_cast<const float4*>(sa + 8);
      float4 f3 = *reinterpret_cast<const float4*>(sa + 12);
      s16x8 o0, o1;
      o0[0] = (short)f2bf(f0.x); o0[1] = (short)f2bf(f0.y);
      o0[2] = (short)f2bf(f0.z); o0[3] = (short)f2bf(f0.w);
      o0[4] = (short)f2bf(f1.x); o0[5] = (short)f2bf(f1.y);
      o0[6] = (short)f2bf(f1.z); o0[7] = (short)f2bf(f1.w);
      o1[0] = (short)f2bf(f2.x); o1[1] = (short)f2bf(f2.y);
      o1[2] = (short)f2bf(f2.z); o1[3] = (short)f2bf(f2.w);
      o1[4] = (short)f2bf(f3.x); o1[5] = (short)f2bf(f3.y);
      o1[6] = (short)f2bf(f3.z); o1[7] = (short)f2bf(f3.w);
      const unsigned short* sb = Bt + (size_t)(n0 + sr) * WD_ + k0 + sc;
      s16x8 w0 = *reinterpret_cast<const s16x8*>(sb);
      s16x8 w1 = *reinterpret_cast<const s16x8*>(sb + 8);
      *reinterpret_cast<s16x8*>(&As[sr][sc]) = o0;
      *reinterpret_cast<s16x8*>(&As[sr][sc + 8]) = o1;
      *reinterpret_cast<s16x8*>(&Bs[sr][sc]) = w0;
      *reinterpret_cast<s16x8*>(&Bs[sr][sc + 8]) = w1;
    }
    __syncthreads();
    bf16x8 aF[4], bF[4];
#pragma unroll
    for (int i = 0; i < 4; ++i)
      aF[i] = ld_bf8(&As[wm + i * 16 + l16][lhi * 8]);
#pragma unroll
    for (int j = 0; j < 4; ++j)
      bF[j] = ld_bf8(&Bs[wn + j * 16 + l16][lhi * 8]);
#pragma unroll
    for (int i = 0; i < 4; ++i)
#pragma unroll
      for (int j = 0; j < 4; ++j)
        acc[i][j] = mfma16(aF[i], bF[j], acc[i][j]);
    __syncthreads();
  }

#pragma unroll
  for (int i = 0; i < 4; ++i) {
#pragma unroll
    for (int j = 0; j < 4; ++j) {
#pragma unroll
      for (int r = 0; r < 4; ++r) {
        int m = m0 + wm + i * 16 + lhi * 4 + r;
        int n = n0 + wn + j * 16 + l16;
        float v = acc[i][j][r] + bias[n];
        unsigned short bv = f2bf(v);
        if (z == 0) {
          Qb[(size_t)m * DM_ + n] = bv;
        } else if (z == 1) {
          Kb[(size_t)m * DM_ + n] = bv;
        } else {
          int b = m >> 10, s = m & (S_ - 1);
          int h = n >> 6, d = n & (DK_ - 1);
          Vt[((size_t)(b * H_ + h) * DK_ + d) * S_ + s] = bv;
        }
      }
    }
  }
}

// ---------------- fused attention: scores + softmax + P-write + PV ----------------
// grid (S/32, B*H), 512 threads (8 waves). Block handles 32 q-rows of one head.
// Phase 1: wave w computes QK^T/8 for k-cols [w*128, w*128+128) (regs).
// Phase 2: block softmax; write fp32 P to d_out AND bf16 P to LDS.
// Phase 3: wave w = (i2,j2) computes X[32x64] sub-tile (16x16), K=1024 from LDS/global V^T.
__global__ __launch_bounds__(512) void k_attn(
    const unsigned short* __restrict__ Qb, const unsigned short* __restrict__ Kb,
    const unsigned short* __restrict__ Vt, float* __restrict__ P,
    unsigned short* __restrict__ Xb) {
  __shared__ unsigned short Qs[32][72];
  __shared__ unsigned short Plds[32][1032];
  __shared__ float red[32][8];
  __shared__ float rowM[32];
  __shared__ float rowS[32];
  const int t = threadIdx.x;
  const int lane = t & 63, wid = t >> 6;
  const int l16 = lane & 15, lhi = lane >> 4;
  const int bh = blockIdx.y;
  const int b = bh >> 4, h = bh & 15;
  const int q0 = blockIdx.x * 32;
  const unsigned short* Qbase = Qb + ((size_t)(b * S_ + q0) * DM_ + h * DK_);
  const unsigned short* Kbase = Kb + ((size_t)(b * S_) * DM_ + h * DK_);

  if (t < 256) {
    int r = t >> 3, c = (t & 7) * 8;
    *reinterpret_cast<s16x8*>(&Qs[r][c]) =
        *reinterpret_cast<const s16x8*>(Qbase + (size_t)r * DM_ + c);
  }
  __syncthreads();

  f32x4 acc[2][8] = {};
  const int n0 = wid * 128;
#pragma unroll
  for (int ks = 0; ks < 2; ++ks) {
    bf16x8 aF[2];
#pragma unroll
    for (int i = 0; i < 2; ++i)
      aF[i] = ld_bf8(&Qs[i * 16 + l16][ks * 32 + lhi * 8]);
#pragma unroll
    for (int j = 0; j < 8; ++j) {
      bf16x8 bF = *reinterpret_cast<const bf16x8*>(
          Kbase + (size_t)(n0 + j * 16 + l16) * DM_ + ks * 32 + lhi * 8);
#pragma unroll
      for (int i = 0; i < 2; ++i)
        acc[i][j] = mfma16(aF[i], bF, acc[i][j]);
    }
  }

#pragma unroll
  for (int i = 0; i < 2; ++i)
#pragma unroll
    for (int j = 0; j < 8; ++j)
#pragma unroll
      for (int r = 0; r < 4; ++r) acc[i][j][r] *= 0.125f;

  // row max: 16-lane butterfly within wave, cross-wave via LDS
#pragma unroll
  for (int i = 0; i < 2; ++i) {
#pragma unroll
    for (int r = 0; r < 4; ++r) {
      float m = acc[i][0][r];
#pragma unroll
      for (int j = 1; j < 8; ++j) m = fmaxf(m, acc[i][j][r]);
      for (int off = 1; off < 16; off <<= 1) m = fmaxf(m, __shfl_xor(m, off));
      if (l16 == 0) red[i * 16 + lhi * 4 + r][wid] = m;
    }
  }
  __syncthreads();
  if (t < 32) {
    float m = red[t][0];
#pragma unroll
    for (int w = 1; w < 8; ++w) m = fmaxf(m, red[t][w]);
    rowM[t] = m;
  }
  __syncthreads();

  // exp + row sum
#pragma unroll
  for (int i = 0; i < 2; ++i) {
#pragma unroll
    for (int r = 0; r < 4; ++r) {
      int q = i * 16 + lhi * 4 + r;
      float mq = rowM[q];
      float s = 0.f;
#pragma unroll
      for (int j = 0; j < 8; ++j) {
        float e = __expf(acc[i][j][r] - mq);
        acc[i][j][r] = e;
        s += e;
      }
      for (int off = 1; off < 16; off <<= 1) s += __shfl_xor(s, off);
      if (l16 == 0) red[q][wid] = s;
    }
  }
  __syncthreads();
  if (t < 32) {
    float s = red[t][0];
#pragma unroll
    for (int w = 1; w < 8; ++w) s += red[t][w];
    rowS[t] = s;
  }
  __syncthreads();

  // normalize; write fp32 P to global + bf16 P to LDS
#pragma unroll
  for (int i = 0; i < 2; ++i) {
#pragma unroll
    for (int r = 0; r < 4; ++r) {
      int q = i * 16 + lhi * 4 + r;
      float inv = 1.f / rowS[q];
      float* prow = P + ((size_t)bh * S_ + q0 + q) * S_ + n0;
#pragma unroll
      for (int j = 0; j < 8; ++j) {
        float v = acc[i][j][r] * inv;
        prow[j * 16 + l16] = v;
        Plds[q][n0 + j * 16 + l16] = f2bf(v);
      }
    }
  }
  __syncthreads();

  // PV: wave (i2,j2) computes 16x16 tile of X[32x64]; two K-chains for ILP
  const int i2 = wid >> 2, j2 = wid & 3;
  const unsigned short* Vrow = Vt + ((size_t)bh * DK_ + j2 * 16 + l16) * S_;
  f32x4 acc0 = {}, acc1 = {};
#pragma unroll 4
  for (int k0 = 0; k0 < S_; k0 += 64) {
    bf16x8 a0 = ld_bf8(&Plds[i2 * 16 + l16][k0 + lhi * 8]);
    bf16x8 v0 = ld_bf8(Vrow + k0 + lhi * 8);
    acc0 = mfma16(a0, v0, acc0);
    bf16x8 a1 = ld_bf8(&Plds[i2 * 16 + l16][k0 + 32 + lhi * 8]);
    bf16x8 v1 = ld_bf8(Vrow + k0 + 32 + lhi * 8);
    acc1 = mfma16(a1, v1, acc1);
  }
  acc0 += acc1;
#pragma unroll
  for (int r = 0; r < 4; ++r) {
    int s = q0 + i2 * 16 + lhi * 4 + r;
    Xb[(size_t)(b * S_ + s) * DM_ + h * DK_ + j2 * 16 + l16] = f2bf(acc0[r]);
  }
}

// ---------------- output projection: out = Xb[M,1024] @ Wot^T + bo (fp32) ----------------
__global__ __launch_bounds__(256) void k_gemm_out(
    const unsigned short* __restrict__ A, const unsigned short* __restrict__ Bt,
    const float* __restrict__ bias, float* __restrict__ out) {
  __shared__ unsigned short As[128][40];
  __shared__ unsigned short Bs[128][40];
  const int t = threadIdx.x;
  const int lane = t & 63, wid = t >> 6;
  const int l16 = lane & 15, lhi = lane >> 4;
  const int m0 = blockIdx.y * 128, n0 = blockIdx.x * 128;
  const int wm = (wid >> 1) * 64, wn = (wid & 1) * 64;

  f32x4 acc[4][4] = {};
  const int sr = t >> 1, sc = (t & 1) * 16;

  for (int k0 = 0; k0 < DM_; k0 += 32) {
    {
      const unsigned short* sa = A + (size_t)(m0 + sr) * DM_ + k0 + sc;
      s16x8 a0 = *reinterpret_cast<const s16x8*>(sa);
      s16x8 a1 = *reinterpret_cast<const s16x8*>(sa + 8);
      const unsigned short* sb = Bt + (size_t)(n0 + sr) * DM_ + k0 + sc;
      s16x8 b0 = *reinterpret_cast<const s16x8*>(sb);
      s16x8 b1 = *reinterpret_cast<const s16x8*>(sb + 8);
      *reinterpret_cast<s16x8*>(&As[sr][sc]) = a0;
      *reinterpret_cast<s16x8*>(&As[sr][sc + 8]) = a1;
      *reinterpret_cast<s16x8*>(&Bs[sr][sc]) = b0;
      *reinterpret_cast<s16x8*>(&Bs[sr][sc + 8]) = b1;
    }
    __syncthreads();
    bf16x8 aF[4], bF[4];
#pragma unroll
    for (int i = 0; i < 4; ++i)
      aF[i] = ld_bf8(&As[wm + i * 16 + l16][lhi * 8]);
#pragma unroll
    for (int j = 0; j < 4; ++j)
      bF[j] = ld_bf8(&Bs[wn + j * 16 + l16][lhi * 8]);
#pragma unroll
    for (int i = 0; i < 4; ++i)
#pragma unroll
      for (int j = 0; j < 4; ++j)
        acc[i][j] = mfma16(aF[i], bF[j], acc[i][j]);
    __syncthreads();
  }

#pragma unroll
  for (int i = 0; i < 4; ++i)
#pragma unroll
    for (int j = 0; j < 4; ++j)
#pragma unroll
      for (int r = 0; r < 4; ++r) {
        int m = m0 + wm + i * 16 + lhi * 4 + r;
        int n = n0 + wn + j * 16 + l16;
        out[(size_t)m * DM_ + n] = acc[i][j][r] + bias[n];
      }
}

// ---------------- launch ----------------

extern "C" void kernel_launch(void* const* d_in, const int* in_sizes, int n_in,
                              void* d_out, int out_size, void* d_ws, size_t ws_size,
                              hipStream_t stream) {
  const float* query = (const float*)d_in[0];
  const float* key   = (const float*)d_in[1];
  const float* value = (const float*)d_in[2];
  const float* Wq = (const float*)d_in[3];
  const float* bq = (const float*)d_in[4];
  const float* Wk = (const float*)d_in[5];
  const float* bk = (const float*)d_in[6];
  const float* Wv = (const float*)d_in[7];
  const float* bv = (const float*)d_in[8];
  const float* Wo = (const float*)d_in[9];
  const float* bo = (const float*)d_in[10];

  char* ws = (char*)d_ws;
  size_t off = 0;
  auto alloc = [&](size_t bytes) {
    void* p = ws + off;
    off += (bytes + 255) & ~(size_t)255;
    return p;
  };
  unsigned short* Wqt = (unsigned short*)alloc((size_t)DM_ * WD_ * 2);
  unsigned short* Wkt = (unsigned short*)alloc((size_t)DM_ * WD_ * 2);
  unsigned short* Wvt = (unsigned short*)alloc((size_t)DM_ * WD_ * 2);
  unsigned short* Wot = (unsigned short*)alloc((size_t)DM_ * DM_ * 2);
  unsigned short* Qb  = (unsigned short*)alloc((size_t)B_ * S_ * DM_ * 2);
  unsigned short* Kb  = (unsigned short*)alloc((size_t)B_ * S_ * DM_ * 2);
  unsigned short* Vt  = (unsigned short*)alloc((size_t)B_ * H_ * DK_ * S_ * 2);
  unsigned short* Xb  = (unsigned short*)alloc((size_t)B_ * S_ * DM_ * 2);

  float* out = (float*)d_out;
  float* P = out + (size_t)B_ * S_ * DM_;  // p_attn region

  k_tconv<<<dim3(DM_ / 32, WD_ / 32), dim3(32, 8), 0, stream>>>(Wq, Wqt, WD_, DM_);
  k_tconv<<<dim3(DM_ / 32, WD_ / 32), dim3(32, 8), 0, stream>>>(Wk, Wkt, WD_, DM_);
  k_tconv<<<dim3(DM_ / 32, WD_ / 32), dim3(32, 8), 0, stream>>>(Wv, Wvt, WD_, DM_);
  k_tconv<<<dim3(DM_ / 32, DM_ / 32), dim3(32, 8), 0, stream>>>(Wo, Wot, DM_, DM_);

  const int M = B_ * S_;
  k_gemm_qkv<<<dim3(DM_ / 128, M / 128, 3), 256, 0, stream>>>(
      query, key, value, Wqt, Wkt, Wvt, bq, bk, bv, Qb, Kb, Vt);

  k_attn<<<dim3(S_ / 32, B_ * H_), 512, 0, stream>>>(Qb, Kb, Vt, P, Xb);

  k_gemm_out<<<dim3(DM_ / 128, M / 128), 256, 0, stream>>>(Xb, Wot, bo, out);
}

// Round 3
// 425.649 us; speedup vs baseline: 1.1955x; 1.0649x over previous
//
#include <hip/hip_runtime.h>
#include <hip/hip_bf16.h>
#include <cstdint>
#include <cstddef>

// MHA forward: out = (softmax(QK^T/8) V) Wo + bo, plus p_attn (fp32).
// B=8, S=1024, H=16, DK=64, D_MODEL=1024, WORD_DIM=768. Inputs fp32.
// bf16 MFMA 16x16x32, fp32 accumulate.
// R3: pre-convert acts; global_load_lds GEMMs; swapped-QK^T attn (vector P stores).

#define H_ 16
#define DK_ 64
#define DM_ 1024
#define WD_ 768
#define B_ 8
#define S_ 1024

typedef float f32x4 __attribute__((ext_vector_type(4)));
typedef __bf16 bf16x8 __attribute__((ext_vector_type(8)));
typedef short s16x8 __attribute__((ext_vector_type(8)));

__device__ __forceinline__ unsigned short f2bf(float x) {
  unsigned int u = __builtin_bit_cast(unsigned int, x);
  u += 0x7FFFu + ((u >> 16) & 1u);  // RNE
  return (unsigned short)(u >> 16);
}

__device__ __forceinline__ f32x4 mfma16(bf16x8 a, bf16x8 b, f32x4 c) {
  return __builtin_amdgcn_mfma_f32_16x16x32_bf16(a, b, c, 0, 0, 0);
}

__device__ __forceinline__ bf16x8 ld_bf8(const unsigned short* p) {
  return *reinterpret_cast<const bf16x8*>(p);
}

#define GLOAD_LDS16(g, l)                                            \
  __builtin_amdgcn_global_load_lds(                                  \
      (const __attribute__((address_space(1))) void*)(g),            \
      (__attribute__((address_space(3))) void*)(l), 16, 0, 0)

// ---------------- fp32 -> bf16 conversion (z selects tensor) ----------------
__global__ void k_conv3(const float* __restrict__ q, const float* __restrict__ k,
                        const float* __restrict__ v, unsigned short* __restrict__ qo,
                        unsigned short* __restrict__ ko, unsigned short* __restrict__ vo,
                        int n) {
  const float* in = blockIdx.y == 0 ? q : blockIdx.y == 1 ? k : v;
  unsigned short* out = blockIdx.y == 0 ? qo : blockIdx.y == 1 ? ko : vo;
  int i0 = (blockIdx.x * blockDim.x + threadIdx.x) * 8;
  int stride = gridDim.x * blockDim.x * 8;
  for (int i = i0; i < n; i += stride) {
    float4 a = *reinterpret_cast<const float4*>(in + i);
    float4 b = *reinterpret_cast<const float4*>(in + i + 4);
    s16x8 o;
    o[0] = (short)f2bf(a.x); o[1] = (short)f2bf(a.y);
    o[2] = (short)f2bf(a.z); o[3] = (short)f2bf(a.w);
    o[4] = (short)f2bf(b.x); o[5] = (short)f2bf(b.y);
    o[6] = (short)f2bf(b.z); o[7] = (short)f2bf(b.w);
    *reinterpret_cast<s16x8*>(out + i) = o;
  }
}

// W[K][N] fp32 -> Wt[N][K] bf16 (transpose + convert), 32x32 tiles
__global__ void k_tconv(const float* __restrict__ W,
                        unsigned short* __restrict__ Wt, int K, int N) {
  __shared__ float t[32][33];
  int n0 = blockIdx.x * 32, k0 = blockIdx.y * 32;
  int tx = threadIdx.x, ty = threadIdx.y;
  for (int dy = ty; dy < 32; dy += 8)
    t[dy][tx] = W[(size_t)(k0 + dy) * N + n0 + tx];
  __syncthreads();
  for (int dy = ty; dy < 32; dy += 8)
    Wt[(size_t)(n0 + dy) * K + k0 + tx] = f2bf(t[tx][dy]);
}

__global__ void k_tconv3(const float* __restrict__ Wq, const float* __restrict__ Wk,
                         const float* __restrict__ Wv, unsigned short* __restrict__ Wqt,
                         unsigned short* __restrict__ Wkt, unsigned short* __restrict__ Wvt) {
  __shared__ float t[32][33];
  const float* W = blockIdx.z == 0 ? Wq : blockIdx.z == 1 ? Wk : Wv;
  unsigned short* Wt = blockIdx.z == 0 ? Wqt : blockIdx.z == 1 ? Wkt : Wvt;
  int n0 = blockIdx.x * 32, k0 = blockIdx.y * 32;
  int tx = threadIdx.x, ty = threadIdx.y;
  for (int dy = ty; dy < 32; dy += 8)
    t[dy][tx] = W[(size_t)(k0 + dy) * DM_ + n0 + tx];
  __syncthreads();
  for (int dy = ty; dy < 32; dy += 8)
    Wt[(size_t)(n0 + dy) * WD_ + k0 + tx] = f2bf(t[tx][dy]);
}

// ---------------- generic projection GEMM (m97-style staging) ----------------
// C = A[M,K] bf16 @ Wt[N,K]^T bf16 + bias. 128x128 tile, 4 waves, BK=32.
// MODE 0: bf16 [M][DM_] row-major (SWAP=1, ushort4 stores)  -- Q/K proj (z picks set)
// MODE 1: bf16 Vt [B,H,DK,S]       (SWAP=0, ushort4 along s) -- V proj
// MODE 2: fp32 [M][DM_] + bias     (SWAP=1, float4 stores)   -- out proj
template <int SWAP, int MODE, int K>
__global__ __launch_bounds__(256) void k_proj(
    const unsigned short* __restrict__ A0, const unsigned short* __restrict__ A1,
    const unsigned short* __restrict__ W0, const unsigned short* __restrict__ W1,
    const float* __restrict__ bias0, const float* __restrict__ bias1,
    unsigned short* __restrict__ Ob0, unsigned short* __restrict__ Ob1,
    float* __restrict__ Of) {
  const int z = blockIdx.z;
  const unsigned short* A = z ? A1 : A0;
  const unsigned short* Bt = z ? W1 : W0;
  const float* bias = z ? bias1 : bias0;
  unsigned short* Ob = z ? Ob1 : Ob0;

  __shared__ unsigned short As[128 * 32];
  __shared__ unsigned short Bs[128 * 32];
  const int t = threadIdx.x;
  const int lane = t & 63, w = t >> 6;
  const int l16 = lane & 15, lhi = lane >> 4;
  const int m0 = blockIdx.y * 128, n0 = blockIdx.x * 128;
  const int wm = (w >> 1) * 64, wn = (w & 1) * 64;

  f32x4 acc[4][4] = {};
  const int srow = w * 32 + (lane >> 2);
  const int scol = (lane & 3) * 8;

  for (int k0 = 0; k0 < K; k0 += 32) {
    GLOAD_LDS16(A + (size_t)(m0 + srow) * K + k0 + scol, &As[(w * 32) * 32]);
    GLOAD_LDS16(A + (size_t)(m0 + srow + 16) * K + k0 + scol, &As[(w * 32 + 16) * 32]);
    GLOAD_LDS16(Bt + (size_t)(n0 + srow) * K + k0 + scol, &Bs[(w * 32) * 32]);
    GLOAD_LDS16(Bt + (size_t)(n0 + srow + 16) * K + k0 + scol, &Bs[(w * 32 + 16) * 32]);
    __syncthreads();
    bf16x8 aF[4], bF[4];
#pragma unroll
    for (int i = 0; i < 4; ++i)
      aF[i] = *reinterpret_cast<const bf16x8*>(&As[(wm + i * 16 + l16) * 32 + lhi * 8]);
#pragma unroll
    for (int j = 0; j < 4; ++j)
      bF[j] = *reinterpret_cast<const bf16x8*>(&Bs[(wn + j * 16 + l16) * 32 + lhi * 8]);
#pragma unroll
    for (int i = 0; i < 4; ++i)
#pragma unroll
      for (int j = 0; j < 4; ++j)
        acc[i][j] = SWAP ? mfma16(bF[j], aF[i], acc[i][j])
                         : mfma16(aF[i], bF[j], acc[i][j]);
    __syncthreads();
  }

#pragma unroll
  for (int i = 0; i < 4; ++i) {
#pragma unroll
    for (int j = 0; j < 4; ++j) {
      if (MODE == 0) {
        int m = m0 + wm + i * 16 + l16;
        int nb = n0 + wn + j * 16 + lhi * 4;
        float4 bb = *reinterpret_cast<const float4*>(&bias[nb]);
        ushort4 o;
        o.x = f2bf(acc[i][j][0] + bb.x);
        o.y = f2bf(acc[i][j][1] + bb.y);
        o.z = f2bf(acc[i][j][2] + bb.z);
        o.w = f2bf(acc[i][j][3] + bb.w);
        *reinterpret_cast<ushort4*>(&Ob[(size_t)m * DM_ + nb]) = o;
      } else if (MODE == 2) {
        int m = m0 + wm + i * 16 + l16;
        int nb = n0 + wn + j * 16 + lhi * 4;
        float4 bb = *reinterpret_cast<const float4*>(&bias[nb]);
        float4 o;
        o.x = acc[i][j][0] + bb.x;
        o.y = acc[i][j][1] + bb.y;
        o.z = acc[i][j][2] + bb.z;
        o.w = acc[i][j][3] + bb.w;
        *reinterpret_cast<float4*>(&Of[(size_t)m * DM_ + nb]) = o;
      } else {
        int mb = m0 + wm + i * 16 + lhi * 4;
        int n = n0 + wn + j * 16 + l16;
        int b = mb >> 10, s = mb & (S_ - 1);
        int h = n >> 6, d = n & (DK_ - 1);
        float bn = bias[n];
        ushort4 o;
        o.x = f2bf(acc[i][j][0] + bn);
        o.y = f2bf(acc[i][j][1] + bn);
        o.z = f2bf(acc[i][j][2] + bn);
        o.w = f2bf(acc[i][j][3] + bn);
        *reinterpret_cast<ushort4*>(
            &Ob[((size_t)((b * H_ + h) * DK_ + d)) * S_ + s]) = o;
      }
    }
  }
}

// ---------------- fused attention: swapped QK^T + softmax + P-write + PV ----------------
// grid (S/32, B*H), 512 threads (8 waves). Block: 32 q-rows of one head.
// Swapped mfma(K,Q) => lane holds 4 CONSECUTIVE k per acc reg => float4 P stores.
__global__ __launch_bounds__(512, 4) void k_attn(
    const unsigned short* __restrict__ Qb, const unsigned short* __restrict__ Kb,
    const unsigned short* __restrict__ Vt, float* __restrict__ P,
    unsigned short* __restrict__ Xb) {
  __shared__ unsigned short Qs[32][72];
  __shared__ unsigned short Plds[32][1032];
  __shared__ float red[32][9];
  __shared__ float rowM[32];
  __shared__ float rowS[32];
  const int t = threadIdx.x;
  const int lane = t & 63, wid = t >> 6;
  const int l16 = lane & 15, lhi = lane >> 4;
  const int bh = blockIdx.y;
  const int b = bh >> 4, h = bh & 15;
  const int q0 = blockIdx.x * 32;
  const unsigned short* Qbase = Qb + ((size_t)(b * S_ + q0) * DM_ + h * DK_);
  const unsigned short* Kbase = Kb + ((size_t)(b * S_) * DM_ + h * DK_);

  if (t < 256) {
    int r = t >> 3, c = (t & 7) * 8;
    *reinterpret_cast<s16x8*>(&Qs[r][c]) =
        *reinterpret_cast<const s16x8*>(Qbase + (size_t)r * DM_ + c);
  }
  __syncthreads();

  // acc[i][j][r] = S[q = q0+i*16+l16][k = n0+j*16+lhi*4+r]
  f32x4 acc[2][8] = {};
  const int n0 = wid * 128;
#pragma unroll
  for (int ks = 0; ks < 2; ++ks) {
    bf16x8 qf[2];
#pragma unroll
    for (int i = 0; i < 2; ++i)
      qf[i] = ld_bf8(&Qs[i * 16 + l16][ks * 32 + lhi * 8]);
#pragma unroll
    for (int j = 0; j < 8; ++j) {
      bf16x8 kf = *reinterpret_cast<const bf16x8*>(
          Kbase + (size_t)(n0 + j * 16 + l16) * DM_ + ks * 32 + lhi * 8);
#pragma unroll
      for (int i = 0; i < 2; ++i)
        acc[i][j] = mfma16(kf, qf[i], acc[i][j]);
    }
  }

  // scale + in-lane max + 2-shuffle reduce (lanes sharing l16)
#pragma unroll
  for (int i = 0; i < 2; ++i) {
    float mx = -3.4e38f;
#pragma unroll
    for (int j = 0; j < 8; ++j)
#pragma unroll
      for (int r = 0; r < 4; ++r) {
        acc[i][j][r] *= 0.125f;
        mx = fmaxf(mx, acc[i][j][r]);
      }
    mx = fmaxf(mx, __shfl_xor(mx, 16));
    mx = fmaxf(mx, __shfl_xor(mx, 32));
    if (lane < 16) red[i * 16 + l16][wid] = mx;
  }
  __syncthreads();
  if (t < 32) {
    float m = red[t][0];
#pragma unroll
    for (int w = 1; w < 8; ++w) m = fmaxf(m, red[t][w]);
    rowM[t] = m;
  }
  __syncthreads();

  // exp + in-lane sum + 2-shuffle reduce
#pragma unroll
  for (int i = 0; i < 2; ++i) {
    float mq = rowM[i * 16 + l16];
    float s = 0.f;
#pragma unroll
    for (int j = 0; j < 8; ++j)
#pragma unroll
      for (int r = 0; r < 4; ++r) {
        float e = __expf(acc[i][j][r] - mq);
        acc[i][j][r] = e;
        s += e;
      }
    s += __shfl_xor(s, 16);
    s += __shfl_xor(s, 32);
    if (lane < 16) red[i * 16 + l16][wid] = s;
  }
  __syncthreads();
  if (t < 32) {
    float s = red[t][0];
#pragma unroll
    for (int w = 1; w < 8; ++w) s += red[t][w];
    rowS[t] = s;
  }
  __syncthreads();

  // normalize: float4 global P stores + ushort4 LDS stores
#pragma unroll
  for (int i = 0; i < 2; ++i) {
    float inv = 1.f / rowS[i * 16 + l16];
    float* prow = P + ((size_t)bh * S_ + q0 + i * 16 + l16) * S_;
#pragma unroll
    for (int j = 0; j < 8; ++j) {
      f32x4 v = acc[i][j] * inv;
      *reinterpret_cast<f32x4*>(&prow[n0 + j * 16 + lhi * 4]) = v;
      ushort4 pb;
      pb.x = f2bf(v[0]); pb.y = f2bf(v[1]);
      pb.z = f2bf(v[2]); pb.w = f2bf(v[3]);
      *reinterpret_cast<ushort4*>(&Plds[i * 16 + l16][n0 + j * 16 + lhi * 4]) = pb;
    }
  }
  __syncthreads();

  // PV: wave (i2,j2) computes 16x16 tile of X[32x64]; two K-chains for ILP
  const int i2 = wid >> 2, j2 = wid & 3;
  const unsigned short* Vrow = Vt + ((size_t)bh * DK_ + j2 * 16 + l16) * S_;
  f32x4 acc0 = {}, acc1 = {};
#pragma unroll 4
  for (int k0 = 0; k0 < S_; k0 += 64) {
    bf16x8 a0 = ld_bf8(&Plds[i2 * 16 + l16][k0 + lhi * 8]);
    bf16x8 v0 = ld_bf8(Vrow + k0 + lhi * 8);
    acc0 = mfma16(a0, v0, acc0);
    bf16x8 a1 = ld_bf8(&Plds[i2 * 16 + l16][k0 + 32 + lhi * 8]);
    bf16x8 v1 = ld_bf8(Vrow + k0 + 32 + lhi * 8);
    acc1 = mfma16(a1, v1, acc1);
  }
  acc0 += acc1;
#pragma unroll
  for (int r = 0; r < 4; ++r) {
    int s = q0 + i2 * 16 + lhi * 4 + r;
    Xb[(size_t)(b * S_ + s) * DM_ + h * DK_ + j2 * 16 + l16] = f2bf(acc0[r]);
  }
}

// ---------------- launch ----------------

extern "C" void kernel_launch(void* const* d_in, const int* in_sizes, int n_in,
                              void* d_out, int out_size, void* d_ws, size_t ws_size,
                              hipStream_t stream) {
  const float* query = (const float*)d_in[0];
  const float* key   = (const float*)d_in[1];
  const float* value = (const float*)d_in[2];
  const float* Wq = (const float*)d_in[3];
  const float* bq = (const float*)d_in[4];
  const float* Wk = (const float*)d_in[5];
  const float* bk = (const float*)d_in[6];
  const float* Wv = (const float*)d_in[7];
  const float* bv = (const float*)d_in[8];
  const float* Wo = (const float*)d_in[9];
  const float* bo = (const float*)d_in[10];

  char* ws = (char*)d_ws;
  size_t off = 0;
  auto alloc = [&](size_t bytes) {
    void* p = ws + off;
    off += (bytes + 255) & ~(size_t)255;
    return p;
  };
  unsigned short* qb  = (unsigned short*)alloc((size_t)B_ * S_ * WD_ * 2);
  unsigned short* kb  = (unsigned short*)alloc((size_t)B_ * S_ * WD_ * 2);
  unsigned short* vb  = (unsigned short*)alloc((size_t)B_ * S_ * WD_ * 2);
  unsigned short* Wqt = (unsigned short*)alloc((size_t)DM_ * WD_ * 2);
  unsigned short* Wkt = (unsigned short*)alloc((size_t)DM_ * WD_ * 2);
  unsigned short* Wvt = (unsigned short*)alloc((size_t)DM_ * WD_ * 2);
  unsigned short* Wot = (unsigned short*)alloc((size_t)DM_ * DM_ * 2);
  unsigned short* Qb  = (unsigned short*)alloc((size_t)B_ * S_ * DM_ * 2);
  unsigned short* Kb  = (unsigned short*)alloc((size_t)B_ * S_ * DM_ * 2);
  unsigned short* Vt  = (unsigned short*)alloc((size_t)B_ * H_ * DK_ * S_ * 2);
  unsigned short* Xb  = (unsigned short*)alloc((size_t)B_ * S_ * DM_ * 2);

  float* out = (float*)d_out;
  float* P = out + (size_t)B_ * S_ * DM_;  // p_attn region

  const int nAct = B_ * S_ * WD_;
  k_conv3<<<dim3(1024, 3), 256, 0, stream>>>(query, key, value, qb, kb, vb, nAct);
  k_tconv3<<<dim3(DM_ / 32, WD_ / 32, 3), dim3(32, 8), 0, stream>>>(
      Wq, Wk, Wv, Wqt, Wkt, Wvt);
  k_tconv<<<dim3(DM_ / 32, DM_ / 32), dim3(32, 8), 0, stream>>>(Wo, Wot, DM_, DM_);

  const int M = B_ * S_;
  // Q and K projections (z = 0/1)
  k_proj<1, 0, WD_><<<dim3(DM_ / 128, M / 128, 2), 256, 0, stream>>>(
      qb, kb, Wqt, Wkt, bq, bk, Qb, Kb, nullptr);
  // V projection -> transposed Vt
  k_proj<0, 1, WD_><<<dim3(DM_ / 128, M / 128, 1), 256, 0, stream>>>(
      vb, nullptr, Wvt, nullptr, bv, nullptr, Vt, nullptr, nullptr);

  k_attn<<<dim3(S_ / 32, B_ * H_), 512, 0, stream>>>(Qb, Kb, Vt, P, Xb);

  // output projection
  k_proj<1, 2, DM_><<<dim3(DM_ / 128, M / 128, 1), 256, 0, stream>>>(
      Xb, nullptr, Wot, nullptr, bo, nullptr, nullptr, nullptr, out);
}

// Round 4
// 376.584 us; speedup vs baseline: 1.3512x; 1.1303x over previous
//
#include <hip/hip_runtime.h>
#include <hip/hip_bf16.h>
#include <cstdint>
#include <cstddef>

// MHA forward: out = (softmax(QK^T/8) V) Wo + bo, plus p_attn (fp32).
// B=8, S=1024, H=16, DK=64, D_MODEL=1024, WORD_DIM=768. Inputs fp32.
// bf16 MFMA 16x16x32, fp32 accumulate.
// R4: contiguous P-global writes (from Plds, after PV); XCD swizzle everywhere.

#define H_ 16
#define DK_ 64
#define DM_ 1024
#define WD_ 768
#define B_ 8
#define S_ 1024

typedef float f32x4 __attribute__((ext_vector_type(4)));
typedef __bf16 bf16x8 __attribute__((ext_vector_type(8)));
typedef short s16x8 __attribute__((ext_vector_type(8)));

__device__ __forceinline__ unsigned short f2bf(float x) {
  unsigned int u = __builtin_bit_cast(unsigned int, x);
  u += 0x7FFFu + ((u >> 16) & 1u);  // RNE
  return (unsigned short)(u >> 16);
}

__device__ __forceinline__ float bf2f(unsigned short b) {
  return __builtin_bit_cast(float, (unsigned int)b << 16);
}

__device__ __forceinline__ f32x4 mfma16(bf16x8 a, bf16x8 b, f32x4 c) {
  return __builtin_amdgcn_mfma_f32_16x16x32_bf16(a, b, c, 0, 0, 0);
}

__device__ __forceinline__ bf16x8 ld_bf8(const unsigned short* p) {
  return *reinterpret_cast<const bf16x8*>(p);
}

// bijective XCD swizzle (grid count % 8 == 0): consecutive swizzled ids share an XCD
__device__ __forceinline__ int xcd_swz(int wg, int n) {
  int q = n >> 3;
  return (wg & 7) * q + (wg >> 3);
}

#define GLOAD_LDS16(g, l)                                            \
  __builtin_amdgcn_global_load_lds(                                  \
      (const __attribute__((address_space(1))) void*)(g),            \
      (__attribute__((address_space(3))) void*)(l), 16, 0, 0)

// ---------------- fp32 -> bf16 conversion (y selects tensor) ----------------
__global__ void k_conv3(const float* __restrict__ q, const float* __restrict__ k,
                        const float* __restrict__ v, unsigned short* __restrict__ qo,
                        unsigned short* __restrict__ ko, unsigned short* __restrict__ vo,
                        int n) {
  const float* in = blockIdx.y == 0 ? q : blockIdx.y == 1 ? k : v;
  unsigned short* out = blockIdx.y == 0 ? qo : blockIdx.y == 1 ? ko : vo;
  int i0 = (blockIdx.x * blockDim.x + threadIdx.x) * 8;
  int stride = gridDim.x * blockDim.x * 8;
  for (int i = i0; i < n; i += stride) {
    float4 a = *reinterpret_cast<const float4*>(in + i);
    float4 b = *reinterpret_cast<const float4*>(in + i + 4);
    s16x8 o;
    o[0] = (short)f2bf(a.x); o[1] = (short)f2bf(a.y);
    o[2] = (short)f2bf(a.z); o[3] = (short)f2bf(a.w);
    o[4] = (short)f2bf(b.x); o[5] = (short)f2bf(b.y);
    o[6] = (short)f2bf(b.z); o[7] = (short)f2bf(b.w);
    *reinterpret_cast<s16x8*>(out + i) = o;
  }
}

// W[K][N] fp32 -> Wt[N][K] bf16 (transpose + convert), 32x32 tiles
__global__ void k_tconv(const float* __restrict__ W,
                        unsigned short* __restrict__ Wt, int K, int N) {
  __shared__ float t[32][33];
  int n0 = blockIdx.x * 32, k0 = blockIdx.y * 32;
  int tx = threadIdx.x, ty = threadIdx.y;
  for (int dy = ty; dy < 32; dy += 8)
    t[dy][tx] = W[(size_t)(k0 + dy) * N + n0 + tx];
  __syncthreads();
  for (int dy = ty; dy < 32; dy += 8)
    Wt[(size_t)(n0 + dy) * K + k0 + tx] = f2bf(t[tx][dy]);
}

__global__ void k_tconv3(const float* __restrict__ Wq, const float* __restrict__ Wk,
                         const float* __restrict__ Wv, unsigned short* __restrict__ Wqt,
                         unsigned short* __restrict__ Wkt, unsigned short* __restrict__ Wvt) {
  __shared__ float t[32][33];
  const float* W = blockIdx.z == 0 ? Wq : blockIdx.z == 1 ? Wk : Wv;
  unsigned short* Wt = blockIdx.z == 0 ? Wqt : blockIdx.z == 1 ? Wkt : Wvt;
  int n0 = blockIdx.x * 32, k0 = blockIdx.y * 32;
  int tx = threadIdx.x, ty = threadIdx.y;
  for (int dy = ty; dy < 32; dy += 8)
    t[dy][tx] = W[(size_t)(k0 + dy) * DM_ + n0 + tx];
  __syncthreads();
  for (int dy = ty; dy < 32; dy += 8)
    Wt[(size_t)(n0 + dy) * WD_ + k0 + tx] = f2bf(t[tx][dy]);
}

// ---------------- generic projection GEMM (m97-style staging) ----------------
// C = A[M,K] bf16 @ Wt[N,K]^T bf16 + bias. 128x128 tile, 4 waves, BK=32.
// MODE 0: bf16 [M][DM_] row-major (SWAP=1)  -- Q/K proj (z picks set)
// MODE 1: bf16 Vt [B,H,DK,S]      (SWAP=0)  -- V proj
// MODE 2: fp32 [M][DM_] + bias    (SWAP=1)  -- out proj
template <int SWAP, int MODE, int K>
__global__ __launch_bounds__(256) void k_proj(
    const unsigned short* __restrict__ A0, const unsigned short* __restrict__ A1,
    const unsigned short* __restrict__ W0, const unsigned short* __restrict__ W1,
    const float* __restrict__ bias0, const float* __restrict__ bias1,
    unsigned short* __restrict__ Ob0, unsigned short* __restrict__ Ob1,
    float* __restrict__ Of, int nbx, int nby) {
  const int z = blockIdx.z;
  const unsigned short* A = z ? A1 : A0;
  const unsigned short* Bt = z ? W1 : W0;
  const float* bias = z ? bias1 : bias0;
  unsigned short* Ob = z ? Ob1 : Ob0;

  const int swz = xcd_swz(blockIdx.y * nbx + blockIdx.x, nbx * nby);
  const int m0 = (swz / nbx) * 128, n0 = (swz % nbx) * 128;

  __shared__ unsigned short As[128 * 32];
  __shared__ unsigned short Bs[128 * 32];
  const int t = threadIdx.x;
  const int lane = t & 63, w = t >> 6;
  const int l16 = lane & 15, lhi = lane >> 4;
  const int wm = (w >> 1) * 64, wn = (w & 1) * 64;

  f32x4 acc[4][4] = {};
  const int srow = w * 32 + (lane >> 2);
  const int scol = (lane & 3) * 8;

  for (int k0 = 0; k0 < K; k0 += 32) {
    GLOAD_LDS16(A + (size_t)(m0 + srow) * K + k0 + scol, &As[(w * 32) * 32]);
    GLOAD_LDS16(A + (size_t)(m0 + srow + 16) * K + k0 + scol, &As[(w * 32 + 16) * 32]);
    GLOAD_LDS16(Bt + (size_t)(n0 + srow) * K + k0 + scol, &Bs[(w * 32) * 32]);
    GLOAD_LDS16(Bt + (size_t)(n0 + srow + 16) * K + k0 + scol, &Bs[(w * 32 + 16) * 32]);
    __syncthreads();
    bf16x8 aF[4], bF[4];
#pragma unroll
    for (int i = 0; i < 4; ++i)
      aF[i] = *reinterpret_cast<const bf16x8*>(&As[(wm + i * 16 + l16) * 32 + lhi * 8]);
#pragma unroll
    for (int j = 0; j < 4; ++j)
      bF[j] = *reinterpret_cast<const bf16x8*>(&Bs[(wn + j * 16 + l16) * 32 + lhi * 8]);
#pragma unroll
    for (int i = 0; i < 4; ++i)
#pragma unroll
      for (int j = 0; j < 4; ++j)
        acc[i][j] = SWAP ? mfma16(bF[j], aF[i], acc[i][j])
                         : mfma16(aF[i], bF[j], acc[i][j]);
    __syncthreads();
  }

#pragma unroll
  for (int i = 0; i < 4; ++i) {
#pragma unroll
    for (int j = 0; j < 4; ++j) {
      if (MODE == 0) {
        int m = m0 + wm + i * 16 + l16;
        int nb = n0 + wn + j * 16 + lhi * 4;
        float4 bb = *reinterpret_cast<const float4*>(&bias[nb]);
        ushort4 o;
        o.x = f2bf(acc[i][j][0] + bb.x);
        o.y = f2bf(acc[i][j][1] + bb.y);
        o.z = f2bf(acc[i][j][2] + bb.z);
        o.w = f2bf(acc[i][j][3] + bb.w);
        *reinterpret_cast<ushort4*>(&Ob[(size_t)m * DM_ + nb]) = o;
      } else if (MODE == 2) {
        int m = m0 + wm + i * 16 + l16;
        int nb = n0 + wn + j * 16 + lhi * 4;
        float4 bb = *reinterpret_cast<const float4*>(&bias[nb]);
        float4 o;
        o.x = acc[i][j][0] + bb.x;
        o.y = acc[i][j][1] + bb.y;
        o.z = acc[i][j][2] + bb.z;
        o.w = acc[i][j][3] + bb.w;
        *reinterpret_cast<float4*>(&Of[(size_t)m * DM_ + nb]) = o;
      } else {
        int mb = m0 + wm + i * 16 + lhi * 4;
        int n = n0 + wn + j * 16 + l16;
        int b = mb >> 10, s = mb & (S_ - 1);
        int h = n >> 6, d = n & (DK_ - 1);
        float bn = bias[n];
        ushort4 o;
        o.x = f2bf(acc[i][j][0] + bn);
        o.y = f2bf(acc[i][j][1] + bn);
        o.z = f2bf(acc[i][j][2] + bn);
        o.w = f2bf(acc[i][j][3] + bn);
        *reinterpret_cast<ushort4*>(
            &Ob[((size_t)((b * H_ + h) * DK_ + d)) * S_ + s]) = o;
      }
    }
  }
}

// ---------------- fused attention ----------------
// grid (S/32 * B*H) swizzled so one XCD owns 16 consecutive heads (KV fits its L2).
// Swapped mfma(K,Q): lane holds 4 consecutive k per acc reg.
// P-global written contiguously (1KB/instr) from Plds AFTER PV.
__global__ __launch_bounds__(512, 4) void k_attn(
    const unsigned short* __restrict__ Qb, const unsigned short* __restrict__ Kb,
    const unsigned short* __restrict__ Vt, float* __restrict__ P,
    unsigned short* __restrict__ Xb) {
  __shared__ unsigned short Qs[32][72];
  __shared__ unsigned short Plds[32][1032];
  __shared__ float red[32][9];
  __shared__ float rowM[32];
  __shared__ float rowS[32];
  const int t = threadIdx.x;
  const int lane = t & 63, wid = t >> 6;
  const int l16 = lane & 15, lhi = lane >> 4;

  const int swz = xcd_swz(blockIdx.y * gridDim.x + blockIdx.x,
                          gridDim.x * gridDim.y);
  const int bh = swz / (S_ / 32);
  const int q0 = (swz % (S_ / 32)) * 32;
  const int b = bh >> 4, h = bh & 15;
  const unsigned short* Qbase = Qb + ((size_t)(b * S_ + q0) * DM_ + h * DK_);
  const unsigned short* Kbase = Kb + ((size_t)(b * S_) * DM_ + h * DK_);

  if (t < 256) {
    int r = t >> 3, c = (t & 7) * 8;
    *reinterpret_cast<s16x8*>(&Qs[r][c]) =
        *reinterpret_cast<const s16x8*>(Qbase + (size_t)r * DM_ + c);
  }
  __syncthreads();

  // acc[i][j][r] = S[q = i*16+l16][k = n0+j*16+lhi*4+r]
  f32x4 acc[2][8] = {};
  const int n0 = wid * 128;
#pragma unroll
  for (int ks = 0; ks < 2; ++ks) {
    bf16x8 qf[2];
#pragma unroll
    for (int i = 0; i < 2; ++i)
      qf[i] = ld_bf8(&Qs[i * 16 + l16][ks * 32 + lhi * 8]);
#pragma unroll
    for (int j = 0; j < 8; ++j) {
      bf16x8 kf = *reinterpret_cast<const bf16x8*>(
          Kbase + (size_t)(n0 + j * 16 + l16) * DM_ + ks * 32 + lhi * 8);
#pragma unroll
      for (int i = 0; i < 2; ++i)
        acc[i][j] = mfma16(kf, qf[i], acc[i][j]);
    }
  }

  // scale + in-lane max + 2-shuffle reduce
#pragma unroll
  for (int i = 0; i < 2; ++i) {
    float mx = -3.4e38f;
#pragma unroll
    for (int j = 0; j < 8; ++j)
#pragma unroll
      for (int r = 0; r < 4; ++r) {
        acc[i][j][r] *= 0.125f;
        mx = fmaxf(mx, acc[i][j][r]);
      }
    mx = fmaxf(mx, __shfl_xor(mx, 16));
    mx = fmaxf(mx, __shfl_xor(mx, 32));
    if (lane < 16) red[i * 16 + l16][wid] = mx;
  }
  __syncthreads();
  if (t < 32) {
    float m = red[t][0];
#pragma unroll
    for (int w = 1; w < 8; ++w) m = fmaxf(m, red[t][w]);
    rowM[t] = m;
  }
  __syncthreads();

  // exp + in-lane sum + 2-shuffle reduce
#pragma unroll
  for (int i = 0; i < 2; ++i) {
    float mq = rowM[i * 16 + l16];
    float s = 0.f;
#pragma unroll
    for (int j = 0; j < 8; ++j)
#pragma unroll
      for (int r = 0; r < 4; ++r) {
        float e = __expf(acc[i][j][r] - mq);
        acc[i][j][r] = e;
        s += e;
      }
    s += __shfl_xor(s, 16);
    s += __shfl_xor(s, 32);
    if (lane < 16) red[i * 16 + l16][wid] = s;
  }
  __syncthreads();
  if (t < 32) {
    float s = red[t][0];
#pragma unroll
    for (int w = 1; w < 8; ++w) s += red[t][w];
    rowS[t] = s;
  }
  __syncthreads();

  // normalize -> Plds (bf16) only
#pragma unroll
  for (int i = 0; i < 2; ++i) {
    float inv = 1.f / rowS[i * 16 + l16];
#pragma unroll
    for (int j = 0; j < 8; ++j) {
      f32x4 v = acc[i][j] * inv;
      ushort4 pb;
      pb.x = f2bf(v[0]); pb.y = f2bf(v[1]);
      pb.z = f2bf(v[2]); pb.w = f2bf(v[3]);
      *reinterpret_cast<ushort4*>(&Plds[i * 16 + l16][n0 + j * 16 + lhi * 4]) = pb;
    }
  }
  __syncthreads();

  // PV: wave (i2,j2) computes 16x16 tile of X[32x64]; two K-chains for ILP
  const int i2 = wid >> 2, j2 = wid & 3;
  const unsigned short* Vrow = Vt + ((size_t)bh * DK_ + j2 * 16 + l16) * S_;
  f32x4 acc0 = {}, acc1 = {};
#pragma unroll 4
  for (int k0 = 0; k0 < S_; k0 += 64) {
    bf16x8 a0 = ld_bf8(&Plds[i2 * 16 + l16][k0 + lhi * 8]);
    bf16x8 v0 = ld_bf8(Vrow + k0 + lhi * 8);
    acc0 = mfma16(a0, v0, acc0);
    bf16x8 a1 = ld_bf8(&Plds[i2 * 16 + l16][k0 + 32 + lhi * 8]);
    bf16x8 v1 = ld_bf8(Vrow + k0 + 32 + lhi * 8);
    acc1 = mfma16(a1, v1, acc1);
  }
  acc0 += acc1;

  // P-global write: wave w owns rows 4w..4w+3; fully contiguous 1KB stores
  {
    float* Prow0 = P + ((size_t)bh * S_ + q0) * S_;
#pragma unroll
    for (int rr = 0; rr < 4; ++rr) {
      int q = wid * 4 + rr;
#pragma unroll
      for (int c = 0; c < 4; ++c) {
        ushort4 pv = *reinterpret_cast<const ushort4*>(&Plds[q][c * 256 + lane * 4]);
        float4 o;
        o.x = bf2f(pv.x); o.y = bf2f(pv.y);
        o.z = bf2f(pv.z); o.w = bf2f(pv.w);
        *reinterpret_cast<float4*>(&Prow0[(size_t)q * S_ + c * 256 + lane * 4]) = o;
      }
    }
  }

  // X epilogue
#pragma unroll
  for (int r = 0; r < 4; ++r) {
    int s = q0 + i2 * 16 + lhi * 4 + r;
    Xb[(size_t)(b * S_ + s) * DM_ + h * DK_ + j2 * 16 + l16] = f2bf(acc0[r]);
  }
}

// ---------------- launch ----------------

extern "C" void kernel_launch(void* const* d_in, const int* in_sizes, int n_in,
                              void* d_out, int out_size, void* d_ws, size_t ws_size,
                              hipStream_t stream) {
  const float* query = (const float*)d_in[0];
  const float* key   = (const float*)d_in[1];
  const float* value = (const float*)d_in[2];
  const float* Wq = (const float*)d_in[3];
  const float* bq = (const float*)d_in[4];
  const float* Wk = (const float*)d_in[5];
  const float* bk = (const float*)d_in[6];
  const float* Wv = (const float*)d_in[7];
  const float* bv = (const float*)d_in[8];
  const float* Wo = (const float*)d_in[9];
  const float* bo = (const float*)d_in[10];

  char* ws = (char*)d_ws;
  size_t off = 0;
  auto alloc = [&](size_t bytes) {
    void* p = ws + off;
    off += (bytes + 255) & ~(size_t)255;
    return p;
  };
  unsigned short* qb  = (unsigned short*)alloc((size_t)B_ * S_ * WD_ * 2);
  unsigned short* kb  = (unsigned short*)alloc((size_t)B_ * S_ * WD_ * 2);
  unsigned short* vb  = (unsigned short*)alloc((size_t)B_ * S_ * WD_ * 2);
  unsigned short* Wqt = (unsigned short*)alloc((size_t)DM_ * WD_ * 2);
  unsigned short* Wkt = (unsigned short*)alloc((size_t)DM_ * WD_ * 2);
  unsigned short* Wvt = (unsigned short*)alloc((size_t)DM_ * WD_ * 2);
  unsigned short* Wot = (unsigned short*)alloc((size_t)DM_ * DM_ * 2);
  unsigned short* Qb  = (unsigned short*)alloc((size_t)B_ * S_ * DM_ * 2);
  unsigned short* Kb  = (unsigned short*)alloc((size_t)B_ * S_ * DM_ * 2);
  unsigned short* Vt  = (unsigned short*)alloc((size_t)B_ * H_ * DK_ * S_ * 2);
  unsigned short* Xb  = (unsigned short*)alloc((size_t)B_ * S_ * DM_ * 2);

  float* out = (float*)d_out;
  float* P = out + (size_t)B_ * S_ * DM_;  // p_attn region

  const int nAct = B_ * S_ * WD_;
  k_conv3<<<dim3(1024, 3), 256, 0, stream>>>(query, key, value, qb, kb, vb, nAct);
  k_tconv3<<<dim3(DM_ / 32, WD_ / 32, 3), dim3(32, 8), 0, stream>>>(
      Wq, Wk, Wv, Wqt, Wkt, Wvt);
  k_tconv<<<dim3(DM_ / 32, DM_ / 32), dim3(32, 8), 0, stream>>>(Wo, Wot, DM_, DM_);

  const int M = B_ * S_;
  // Q and K projections (z = 0/1)
  k_proj<1, 0, WD_><<<dim3(DM_ / 128, M / 128, 2), 256, 0, stream>>>(
      qb, kb, Wqt, Wkt, bq, bk, Qb, Kb, nullptr, DM_ / 128, M / 128);
  // V projection -> transposed Vt
  k_proj<0, 1, WD_><<<dim3(DM_ / 128, M / 128, 1), 256, 0, stream>>>(
      vb, nullptr, Wvt, nullptr, bv, nullptr, Vt, nullptr, nullptr, DM_ / 128, M / 128);

  k_attn<<<dim3(S_ / 32, B_ * H_), 512, 0, stream>>>(Qb, Kb, Vt, P, Xb);

  // output projection
  k_proj<1, 2, DM_><<<dim3(DM_ / 128, M / 128, 1), 256, 0, stream>>>(
      Xb, nullptr, Wot, nullptr, bo, nullptr, nullptr, nullptr, out, DM_ / 128, M / 128);
}